// Round 12
// baseline (134.725 us; speedup 1.0000x reference)
//
#include <hip/hip_runtime.h>
#include <hip/hip_bf16.h>

// B=16, C=512, L=1024.
// score[b,i,j] = sum_c k[b,c,i]*q[b,c,j] / 32 ; P = softmax over b (axis=0!)
// out[b,c,j] = sum_i v[b,c,i]*P[b,i,j]
// Pipeline:
//   K0 transpose_convert64: q,k f32 [b][c][l] -> qT,kT bf16 [b][l][c] (64x64, vec)
//   K1 gemm_2b: S'[b][j][i] = (qT . kT^T)/32, bf16  (2 batches folded per block:
//        512 blocks x 32 K-steps == K4's proven profile)
//   K3 convert_v: v f32 -> vB bf16
//   K2 softmax_b: in-place softmax over b on S'
//   K4 gemm_glds: out[b][c][j] = vB . P^T, f32       (128^2 2-phase, R10, 716 TF)
// GEMM core (both K1/K4): 128x128 tile, BK=32 dbuf (32 KiB -> 5 blocks/CU),
// global_load_lds w=16, XOR swizzle slot^=((row>>1)&3) on source AND ds_read,
// bijective XCD chunk remap.

#define LN 1024
#define CC 512
#define BN 16

typedef __attribute__((ext_vector_type(8))) short bf16x8;
typedef __attribute__((ext_vector_type(4))) float f32x4;

static __device__ __forceinline__ unsigned short f2bf(float x) {
  union { float f; unsigned u; } un; un.f = x;
  unsigned r = un.u + 0x7fffu + ((un.u >> 16) & 1u);   // RNE
  return (unsigned short)(r >> 16);
}
static __device__ __forceinline__ float bf2f(unsigned short h) {
  union { unsigned u; float f; } un; un.u = ((unsigned)h) << 16; return un.f;
}

// ---------------- K0: 64x64 transpose-convert, vectorized both sides
__global__ __launch_bounds__(256) void transpose_convert64(
    const float* __restrict__ q, const float* __restrict__ k,
    unsigned short* __restrict__ qT, unsigned short* __restrict__ kT) {
  __shared__ float tile[64][65];
  const int b = blockIdx.z >> 1, mat = blockIdx.z & 1;
  const float* src = mat ? k : q;
  unsigned short* dst = mat ? kT : qT;
  const int l0 = blockIdx.x * 64, c0 = blockIdx.y * 64;
  const int t = threadIdx.x;
  const int lv = (t & 15) * 4, cr = t >> 4;   // read: 16 lanes x float4 per c-row
#pragma unroll
  for (int p = 0; p < 4; ++p) {
    const int c = cr + p * 16;
    const float4 v4 = *(const float4*)(src + ((size_t)b * CC + c0 + c) * LN + l0 + lv);
    tile[c][lv] = v4.x; tile[c][lv + 1] = v4.y;
    tile[c][lv + 2] = v4.z; tile[c][lv + 3] = v4.w;
  }
  __syncthreads();
  const int c8 = (t & 7) * 8, lw = t >> 3;    // write: 8 lanes x bf16x8 per l-row
#pragma unroll
  for (int p = 0; p < 2; ++p) {
    const int l = lw + p * 32;
    bf16x8 o;
#pragma unroll
    for (int i = 0; i < 8; ++i) o[i] = (short)f2bf(tile[c8 + i][l]);  // stride-65: 2-way max
    *(bf16x8*)(dst + ((size_t)b * LN + l0 + l) * CC + c0 + c8) = o;
  }
}

// ---------------- K1: 128^2 2-phase GEMM, TWO batches folded per block.
// C[bz][row][col] = scale * sum_k A[bz][row][k]*B[bz][col][k], bf16 out.
// 512 blocks x 32 K-steps (16 per batch); mid-loop C-write + acc reset at s==15.
template<int LDAv, int LDBv, int LDCv, int NTN, int NTM, int NBQ>
__global__ __launch_bounds__(256, 5) void gemm_2b(
    const unsigned short* __restrict__ A, const unsigned short* __restrict__ B,
    unsigned short* __restrict__ C, float scale,
    size_t strideA, size_t strideB, size_t strideC) {
  __shared__ unsigned short As[2][128 * 32];
  __shared__ unsigned short Bs[2][128 * 32];

  constexpr int nwg = NTN * NTM * NBQ;        // 512, %8==0
  const int f = blockIdx.x + NTN * (blockIdx.y + NTM * blockIdx.z);
  const int wid = (f & 7) * (nwg >> 3) + (f >> 3);
  const int tn = wid % NTN;
  const int tm = (wid / NTN) % NTM;
  const int bz0 = (wid / (NTN * NTM)) * 2;    // XCD chunk = 64 wids = 2 batches (4MB -> L2)

  const int t = threadIdx.x, w = t >> 6, l = t & 63;
  const int wr = w >> 1, wc = w & 1;
  const int lr = l & 15, lks = l >> 4;

  f32x4 acc[4][4];
#pragma unroll
  for (int m = 0; m < 4; ++m)
#pragma unroll
    for (int n = 0; n < 4; ++n) acc[m][n] = (f32x4){0.f, 0.f, 0.f, 0.f};

  const int srow = t >> 2;
  const int sslot = t & 3;

  auto STAGE = [&](int buf, int s) {          // s in [0,32): batch s>>4, k-step s&15
    const int bb = s >> 4, c0 = (s & 15) * 32;
    const unsigned short* Abb = A + (size_t)(bz0 + bb) * strideA;
    const unsigned short* Bbb = B + (size_t)(bz0 + bb) * strideB;
#pragma unroll
    for (int qq = 0; qq < 2; ++qq) {
      const int row = qq * 64 + srow;
      const unsigned short* ga =
          Abb + (size_t)(tm * 128 + row) * LDAv + c0 + ((sslot ^ ((row >> 1) & 3)) * 8);
      __builtin_amdgcn_global_load_lds(
          (const __attribute__((address_space(1))) void*)ga,
          (__attribute__((address_space(3))) void*)&As[buf][qq * 2048 + t * 8],
          16, 0, 0);
    }
#pragma unroll
    for (int qq = 0; qq < 2; ++qq) {
      const int row = qq * 64 + srow;
      const unsigned short* gb =
          Bbb + (size_t)(tn * 128 + row) * LDBv + c0 + ((sslot ^ ((row >> 1) & 3)) * 8);
      __builtin_amdgcn_global_load_lds(
          (const __attribute__((address_space(1))) void*)gb,
          (__attribute__((address_space(3))) void*)&Bs[buf][qq * 2048 + t * 8],
          16, 0, 0);
    }
  };

  auto WRITEC = [&](int bb) {
#pragma unroll
    for (int m = 0; m < 4; ++m)
#pragma unroll
      for (int n = 0; n < 4; ++n)
#pragma unroll
        for (int r = 0; r < 4; ++r) {
          const int row = tm * 128 + wr * 64 + m * 16 + (l >> 4) * 4 + r;
          const int col = tn * 128 + wc * 64 + n * 16 + lr;
          C[(size_t)(bz0 + bb) * strideC + (size_t)row * LDCv + col] =
              f2bf(acc[m][n][r] * scale);
        }
  };

  STAGE(0, 0);
  __syncthreads();

  int cur = 0;
#pragma unroll 1
  for (int s = 0; s < 32; ++s) {
    if (s + 1 < 32) STAGE(cur ^ 1, s + 1);
    bf16x8 af[4], bfr[4];
#pragma unroll
    for (int m = 0; m < 4; ++m) {
      const int r = wr * 64 + m * 16 + lr;
      const int slot = lks ^ ((r >> 1) & 3);
      af[m] = *(const bf16x8*)(&As[cur][r * 32 + slot * 8]);
    }
#pragma unroll
    for (int n = 0; n < 4; ++n) {
      const int r = wc * 64 + n * 16 + lr;
      const int slot = lks ^ ((r >> 1) & 3);
      bfr[n] = *(const bf16x8*)(&Bs[cur][r * 32 + slot * 8]);
    }
#pragma unroll
    for (int m = 0; m < 4; ++m)
#pragma unroll
      for (int n = 0; n < 4; ++n)
        acc[m][n] = __builtin_amdgcn_mfma_f32_16x16x32_bf16(af[m], bfr[n], acc[m][n], 0, 0, 0);
    if (s == 15) {                 // batch 0 done: write + reset, pipeline keeps running
      WRITEC(0);
#pragma unroll
      for (int m = 0; m < 4; ++m)
#pragma unroll
        for (int n = 0; n < 4; ++n) acc[m][n] = (f32x4){0.f, 0.f, 0.f, 0.f};
    }
    __syncthreads();
    cur ^= 1;
  }
  WRITEC(1);
}

// ---------------- K4: 128^2 2-phase batched GEMM (R10, unchanged; 716 TF)
template<int KD, int LDAv, int LDBv, int LDCv, bool OBF, int NTN, int NTM, int NB>
__global__ __launch_bounds__(256, 5) void gemm_glds(
    const unsigned short* __restrict__ A, const unsigned short* __restrict__ B,
    void* __restrict__ Cv, float scale,
    size_t strideA, size_t strideB, size_t strideC) {
  __shared__ unsigned short As[2][128 * 32];
  __shared__ unsigned short Bs[2][128 * 32];

  constexpr int nwg = NTN * NTM * NB;
  const int f = blockIdx.x + NTN * (blockIdx.y + NTM * blockIdx.z);
  const int wid = (f & 7) * (nwg >> 3) + (f >> 3);
  const int tn = wid % NTN;
  const int tm = (wid / NTN) % NTM;
  const int bz = wid / (NTN * NTM);

  const unsigned short* Ab = A + (size_t)bz * strideA;
  const unsigned short* Bb = B + (size_t)bz * strideB;
  const int t = threadIdx.x, w = t >> 6, l = t & 63;
  const int wr = w >> 1, wc = w & 1;
  const int lr = l & 15, lks = l >> 4;

  f32x4 acc[4][4];
#pragma unroll
  for (int m = 0; m < 4; ++m)
#pragma unroll
    for (int n = 0; n < 4; ++n) acc[m][n] = (f32x4){0.f, 0.f, 0.f, 0.f};

  const int srow = t >> 2;
  const int sslot = t & 3;

  auto STAGE = [&](int buf, int step) {
    const int c0 = step * 32;
#pragma unroll
    for (int qq = 0; qq < 2; ++qq) {
      const int row = qq * 64 + srow;
      const unsigned short* ga =
          Ab + (size_t)(tm * 128 + row) * LDAv + c0 + ((sslot ^ ((row >> 1) & 3)) * 8);
      __builtin_amdgcn_global_load_lds(
          (const __attribute__((address_space(1))) void*)ga,
          (__attribute__((address_space(3))) void*)&As[buf][qq * 2048 + t * 8],
          16, 0, 0);
    }
#pragma unroll
    for (int qq = 0; qq < 2; ++qq) {
      const int row = qq * 64 + srow;
      const unsigned short* gb =
          Bb + (size_t)(tn * 128 + row) * LDBv + c0 + ((sslot ^ ((row >> 1) & 3)) * 8);
      __builtin_amdgcn_global_load_lds(
          (const __attribute__((address_space(1))) void*)gb,
          (__attribute__((address_space(3))) void*)&Bs[buf][qq * 2048 + t * 8],
          16, 0, 0);
    }
  };

  STAGE(0, 0);
  __syncthreads();

  const int NSTEP = KD / 32;
  int cur = 0;
#pragma unroll 1
  for (int step = 0; step < NSTEP; ++step) {
    if (step + 1 < NSTEP) STAGE(cur ^ 1, step + 1);
    bf16x8 af[4], bfr[4];
#pragma unroll
    for (int m = 0; m < 4; ++m) {
      const int r = wr * 64 + m * 16 + lr;
      const int slot = lks ^ ((r >> 1) & 3);
      af[m] = *(const bf16x8*)(&As[cur][r * 32 + slot * 8]);
    }
#pragma unroll
    for (int n = 0; n < 4; ++n) {
      const int r = wc * 64 + n * 16 + lr;
      const int slot = lks ^ ((r >> 1) & 3);
      bfr[n] = *(const bf16x8*)(&Bs[cur][r * 32 + slot * 8]);
    }
#pragma unroll
    for (int m = 0; m < 4; ++m)
#pragma unroll
      for (int n = 0; n < 4; ++n)
        acc[m][n] = __builtin_amdgcn_mfma_f32_16x16x32_bf16(af[m], bfr[n], acc[m][n], 0, 0, 0);
    __syncthreads();
    cur ^= 1;
  }

#pragma unroll
  for (int m = 0; m < 4; ++m)
#pragma unroll
    for (int n = 0; n < 4; ++n)
#pragma unroll
      for (int r = 0; r < 4; ++r) {
        const int row = tm * 128 + wr * 64 + m * 16 + (l >> 4) * 4 + r;
        const int col = tn * 128 + wc * 64 + n * 16 + lr;
        if (OBF) {
          ((unsigned short*)Cv)[bz * strideC + (size_t)row * LDCv + col] =
              f2bf(acc[m][n][r] * scale);
        } else {
          ((float*)Cv)[bz * strideC + (size_t)row * LDCv + col] = acc[m][n][r] * scale;
        }
      }
}

// ---------------- K3: v f32 -> bf16 (no transpose)
__global__ __launch_bounds__(256) void convert_v(
    const float* __restrict__ v, unsigned short* __restrict__ vB) {
  const size_t i8 = (size_t)blockIdx.x * 256 + threadIdx.x;
  const float4 a = *(const float4*)(v + i8 * 8);
  const float4 b = *(const float4*)(v + i8 * 8 + 4);
  bf16x8 o;
  o[0] = (short)f2bf(a.x); o[1] = (short)f2bf(a.y);
  o[2] = (short)f2bf(a.z); o[3] = (short)f2bf(a.w);
  o[4] = (short)f2bf(b.x); o[5] = (short)f2bf(b.y);
  o[6] = (short)f2bf(b.z); o[7] = (short)f2bf(b.w);
  *(bf16x8*)(vB + i8 * 8) = o;
}

// ---------------- K2: in-place softmax over b (16 values) at each (j,i)
__global__ __launch_bounds__(256) void softmax_b(unsigned short* __restrict__ SP) {
  const size_t off = ((size_t)blockIdx.x * 256 + threadIdx.x) * 8;
  bf16x8 s[BN];
#pragma unroll
  for (int b = 0; b < BN; ++b)
    s[b] = *(const bf16x8*)(SP + (size_t)b * (LN * LN) + off);
#pragma unroll
  for (int e = 0; e < 8; ++e) {
    float vv[BN];
#pragma unroll
    for (int b = 0; b < BN; ++b) vv[b] = bf2f((unsigned short)s[b][e]);
    float m = vv[0];
#pragma unroll
    for (int b = 1; b < BN; ++b) m = fmaxf(m, vv[b]);
    float tt[BN], sum = 0.f;
#pragma unroll
    for (int b = 0; b < BN; ++b) { tt[b] = __expf(vv[b] - m); sum += tt[b]; }
    const float inv = 1.f / sum;
#pragma unroll
    for (int b = 0; b < BN; ++b) s[b][e] = (short)f2bf(tt[b] * inv);
  }
#pragma unroll
  for (int b = 0; b < BN; ++b)
    *(bf16x8*)(SP + (size_t)b * (LN * LN) + off) = s[b];
}

extern "C" void kernel_launch(void* const* d_in, const int* in_sizes, int n_in,
                              void* d_out, int out_size, void* d_ws, size_t ws_size,
                              hipStream_t stream) {
  const float* q = (const float*)d_in[0];
  const float* k = (const float*)d_in[1];
  const float* v = (const float*)d_in[2];
  float* out = (float*)d_out;

  unsigned short* qT = (unsigned short*)d_ws;            // 16 MiB
  unsigned short* kT = qT + (size_t)BN * LN * CC;        // 16 MiB
  unsigned short* SP = kT + (size_t)BN * LN * CC;        // 32 MiB (S' then P)
  unsigned short* vB = qT;                               // overlay (qT dead after K1)

  transpose_convert64<<<dim3(LN / 64, CC / 64, BN * 2), 256, 0, stream>>>(q, k, qT, kT);
  // K1: S' = (qT . kT^T)/32, bf16. 2 batches/block -> 512 blocks x 32 steps.
  gemm_2b<512, 512, 1024, 8, 8, 8><<<dim3(8, 8, 8), 256, 0, stream>>>(
      qT, kT, SP, 0.03125f,
      (size_t)LN * CC, (size_t)LN * CC, (size_t)LN * LN);
  convert_v<<<dim3((BN * CC * LN) / 8 / 256), 256, 0, stream>>>(v, vB);
  softmax_b<<<dim3((LN * LN) / 8 / 256), 256, 0, stream>>>(SP);
  // K4: out = vB . P^T, f32. M=512, N=1024, K=1024.
  gemm_glds<1024, 1024, 1024, 1024, false, 8, 4, BN><<<dim3(8, 4, BN), 256, 0, stream>>>(
      vB, SP, (void*)out, 1.0f,
      (size_t)CC * LN, (size_t)LN * LN, (size_t)CC * LN);
}

// Round 13
// 99.559 us; speedup vs baseline: 1.3532x; 1.3532x over previous
//
#include <hip/hip_runtime.h>
#include <hip/hip_bf16.h>

// B=16, C=512, L=1024.
// score[b,i,j] = sum_c k[b,c,i]*q[b,c,j] / 32 ; P = softmax over b (axis=0!)
// out[b,c,j] = sum_i v[b,c,i]*P[b,i,j]
// Pipeline:
//   K0 transpose_convert64: q,k f32 [b][c][l] -> qT,kT bf16 [b][l][c]
//   K1 gemm_2bacc: S'[b][j][i] = (qT . kT^T)/32, bf16
//        tile 128x64, grid (16,8,8)=1024 blocks (4/CU), each block streams a
//        BATCH PAIR through one 32-step 2-phase K-loop; two named acc sets;
//        no mid-loop C-write (lesson of R12: 512 blocks = 2/CU killed TLP).
//   K3 convert_v: v f32 -> vB bf16
//   K2 softmax_b: in-place softmax over b on S'
//   K4 gemm_glds: out = vB . P^T, f32 (128^2 2-phase, NSTEP=32, measured-good)
// GEMM core: BK=32 dbuf, global_load_lds w=16, XOR swizzle slot^=((row>>1)&3)
// on source AND ds_read (rule 21), bijective XCD chunk remap.

#define LN 1024
#define CC 512
#define BN 16

typedef __attribute__((ext_vector_type(8))) short bf16x8;
typedef __attribute__((ext_vector_type(4))) float f32x4;

static __device__ __forceinline__ unsigned short f2bf(float x) {
  union { float f; unsigned u; } un; un.f = x;
  unsigned r = un.u + 0x7fffu + ((un.u >> 16) & 1u);   // RNE
  return (unsigned short)(r >> 16);
}
static __device__ __forceinline__ float bf2f(unsigned short h) {
  union { unsigned u; float f; } un; un.u = ((unsigned)h) << 16; return un.f;
}

// ---------------- K0: 64x64 transpose-convert, vectorized both sides
__global__ __launch_bounds__(256) void transpose_convert64(
    const float* __restrict__ q, const float* __restrict__ k,
    unsigned short* __restrict__ qT, unsigned short* __restrict__ kT) {
  __shared__ float tile[64][65];
  const int b = blockIdx.z >> 1, mat = blockIdx.z & 1;
  const float* src = mat ? k : q;
  unsigned short* dst = mat ? kT : qT;
  const int l0 = blockIdx.x * 64, c0 = blockIdx.y * 64;
  const int t = threadIdx.x;
  const int lv = (t & 15) * 4, cr = t >> 4;
#pragma unroll
  for (int p = 0; p < 4; ++p) {
    const int c = cr + p * 16;
    const float4 v4 = *(const float4*)(src + ((size_t)b * CC + c0 + c) * LN + l0 + lv);
    tile[c][lv] = v4.x; tile[c][lv + 1] = v4.y;
    tile[c][lv + 2] = v4.z; tile[c][lv + 3] = v4.w;
  }
  __syncthreads();
  const int c8 = (t & 7) * 8, lw = t >> 3;
#pragma unroll
  for (int p = 0; p < 2; ++p) {
    const int l = lw + p * 32;
    bf16x8 o;
#pragma unroll
    for (int i = 0; i < 8; ++i) o[i] = (short)f2bf(tile[c8 + i][l]);
    *(bf16x8*)(dst + ((size_t)b * LN + l0 + l) * CC + c0 + c8) = o;
  }
}

// ---------------- K1: 128x64-tile GEMM, batch-PAIR per block, 32-step stream.
// C[b][row][col] = scale * sum_k A[b][row][k]*B[b][col][k], bf16 out.
__global__ __launch_bounds__(256, 5) void gemm_2bacc(
    const unsigned short* __restrict__ A, const unsigned short* __restrict__ B,
    unsigned short* __restrict__ C, float scale,
    size_t strideA, size_t strideB, size_t strideC) {
  __shared__ unsigned short As[2][128 * 32];   // 8 KiB x2
  __shared__ unsigned short Bs[2][64 * 32];    // 4 KiB x2   (24 KiB total)

  // grid (16,8,8) = 1024 blocks; bijective XCD chunk remap (1024%8==0)
  const int f = blockIdx.x + 16 * (blockIdx.y + 8 * blockIdx.z);
  const int wid = (f & 7) * 128 + (f >> 3);
  const int tn = wid & 15;            // 16 N-tiles of 64
  const int tm = (wid >> 4) & 7;      // 8 M-tiles of 128
  const int b0 = (wid >> 7) * 2;      // batch pair

  const int t = threadIdx.x, w = t >> 6, l = t & 63;
  const int wr = w >> 1, wc = w & 1;  // wave = 64(M) x 32(N) quadrant
  const int lr = l & 15, lks = l >> 4;

  f32x4 accA[4][2], accB[4][2];
#pragma unroll
  for (int m = 0; m < 4; ++m)
#pragma unroll
    for (int n = 0; n < 2; ++n) {
      accA[m][n] = (f32x4){0.f, 0.f, 0.f, 0.f};
      accB[m][n] = (f32x4){0.f, 0.f, 0.f, 0.f};
    }

  auto STAGE = [&](int buf, int s) {   // s in [0,32): batch b0+(s>>4), k-step s&15
    const int bb = b0 + (s >> 4), c0 = (s & 15) * 32;
    const unsigned short* Abb = A + (size_t)bb * strideA;
    const unsigned short* Bbb = B + (size_t)bb * strideB;
#pragma unroll
    for (int qq = 0; qq < 2; ++qq) {   // A: 128 rows
      const int row = qq * 64 + (t >> 2);
      const unsigned short* ga =
          Abb + (size_t)(tm * 128 + row) * CC + c0 + (((t & 3) ^ ((row >> 1) & 3)) * 8);
      __builtin_amdgcn_global_load_lds(
          (const __attribute__((address_space(1))) void*)ga,
          (__attribute__((address_space(3))) void*)&As[buf][qq * 2048 + t * 8],
          16, 0, 0);
    }
    {                                   // B: 64 rows
      const int row = t >> 2;
      const unsigned short* gb =
          Bbb + (size_t)(tn * 64 + row) * CC + c0 + (((t & 3) ^ ((row >> 1) & 3)) * 8);
      __builtin_amdgcn_global_load_lds(
          (const __attribute__((address_space(1))) void*)gb,
          (__attribute__((address_space(3))) void*)&Bs[buf][t * 8],
          16, 0, 0);
    }
  };

  STAGE(0, 0);
  __syncthreads();

  int cur = 0;
  // ---- batch 0: steps 0..15 accumulate into accA (STAGE streams ahead)
#pragma unroll 1
  for (int s = 0; s < 16; ++s) {
    STAGE(cur ^ 1, s + 1);
    bf16x8 af[4], bfr[2];
#pragma unroll
    for (int m = 0; m < 4; ++m) {
      const int r = wr * 64 + m * 16 + lr;
      af[m] = *(const bf16x8*)(&As[cur][r * 32 + ((lks ^ ((r >> 1) & 3)) * 8)]);
    }
#pragma unroll
    for (int n = 0; n < 2; ++n) {
      const int r = wc * 32 + n * 16 + lr;
      bfr[n] = *(const bf16x8*)(&Bs[cur][r * 32 + ((lks ^ ((r >> 1) & 3)) * 8)]);
    }
#pragma unroll
    for (int m = 0; m < 4; ++m)
#pragma unroll
      for (int n = 0; n < 2; ++n)
        accA[m][n] = __builtin_amdgcn_mfma_f32_16x16x32_bf16(af[m], bfr[n], accA[m][n], 0, 0, 0);
    __syncthreads();
    cur ^= 1;
  }
  // ---- batch 1: steps 16..31 into accB
#pragma unroll 1
  for (int s = 16; s < 32; ++s) {
    if (s + 1 < 32) STAGE(cur ^ 1, s + 1);
    bf16x8 af[4], bfr[2];
#pragma unroll
    for (int m = 0; m < 4; ++m) {
      const int r = wr * 64 + m * 16 + lr;
      af[m] = *(const bf16x8*)(&As[cur][r * 32 + ((lks ^ ((r >> 1) & 3)) * 8)]);
    }
#pragma unroll
    for (int n = 0; n < 2; ++n) {
      const int r = wc * 32 + n * 16 + lr;
      bfr[n] = *(const bf16x8*)(&Bs[cur][r * 32 + ((lks ^ ((r >> 1) & 3)) * 8)]);
    }
#pragma unroll
    for (int m = 0; m < 4; ++m)
#pragma unroll
      for (int n = 0; n < 2; ++n)
        accB[m][n] = __builtin_amdgcn_mfma_f32_16x16x32_bf16(af[m], bfr[n], accB[m][n], 0, 0, 0);
    __syncthreads();
    cur ^= 1;
  }

  // epilogue: both batches. D row=(l>>4)*4+reg (M), col=l&15 (N).
#pragma unroll
  for (int m = 0; m < 4; ++m)
#pragma unroll
    for (int n = 0; n < 2; ++n)
#pragma unroll
      for (int r = 0; r < 4; ++r) {
        const int row = tm * 128 + wr * 64 + m * 16 + (l >> 4) * 4 + r;
        const int col = tn * 64 + wc * 32 + n * 16 + lr;
        C[(size_t)b0 * strideC + (size_t)row * LN + col] = f2bf(accA[m][n][r] * scale);
        C[(size_t)(b0 + 1) * strideC + (size_t)row * LN + col] = f2bf(accB[m][n][r] * scale);
      }
}

// ---------------- K4: 128^2 2-phase batched GEMM (measured-good, unchanged)
template<int KD, int LDAv, int LDBv, int LDCv, bool OBF, int NTN, int NTM, int NB>
__global__ __launch_bounds__(256, 5) void gemm_glds(
    const unsigned short* __restrict__ A, const unsigned short* __restrict__ B,
    void* __restrict__ Cv, float scale,
    size_t strideA, size_t strideB, size_t strideC) {
  __shared__ unsigned short As[2][128 * 32];
  __shared__ unsigned short Bs[2][128 * 32];

  constexpr int nwg = NTN * NTM * NB;
  const int f = blockIdx.x + NTN * (blockIdx.y + NTM * blockIdx.z);
  const int wid = (f & 7) * (nwg >> 3) + (f >> 3);
  const int tn = wid % NTN;
  const int tm = (wid / NTN) % NTM;
  const int bz = wid / (NTN * NTM);

  const unsigned short* Ab = A + (size_t)bz * strideA;
  const unsigned short* Bb = B + (size_t)bz * strideB;
  const int t = threadIdx.x, w = t >> 6, l = t & 63;
  const int wr = w >> 1, wc = w & 1;
  const int lr = l & 15, lks = l >> 4;

  f32x4 acc[4][4];
#pragma unroll
  for (int m = 0; m < 4; ++m)
#pragma unroll
    for (int n = 0; n < 4; ++n) acc[m][n] = (f32x4){0.f, 0.f, 0.f, 0.f};

  const int srow = t >> 2;
  const int sslot = t & 3;

  auto STAGE = [&](int buf, int step) {
    const int c0 = step * 32;
#pragma unroll
    for (int qq = 0; qq < 2; ++qq) {
      const int row = qq * 64 + srow;
      const unsigned short* ga =
          Ab + (size_t)(tm * 128 + row) * LDAv + c0 + ((sslot ^ ((row >> 1) & 3)) * 8);
      __builtin_amdgcn_global_load_lds(
          (const __attribute__((address_space(1))) void*)ga,
          (__attribute__((address_space(3))) void*)&As[buf][qq * 2048 + t * 8],
          16, 0, 0);
    }
#pragma unroll
    for (int qq = 0; qq < 2; ++qq) {
      const int row = qq * 64 + srow;
      const unsigned short* gb =
          Bb + (size_t)(tn * 128 + row) * LDBv + c0 + ((sslot ^ ((row >> 1) & 3)) * 8);
      __builtin_amdgcn_global_load_lds(
          (const __attribute__((address_space(1))) void*)gb,
          (__attribute__((address_space(3))) void*)&Bs[buf][qq * 2048 + t * 8],
          16, 0, 0);
    }
  };

  STAGE(0, 0);
  __syncthreads();

  const int NSTEP = KD / 32;
  int cur = 0;
#pragma unroll 1
  for (int step = 0; step < NSTEP; ++step) {
    if (step + 1 < NSTEP) STAGE(cur ^ 1, step + 1);
    bf16x8 af[4], bfr[4];
#pragma unroll
    for (int m = 0; m < 4; ++m) {
      const int r = wr * 64 + m * 16 + lr;
      const int slot = lks ^ ((r >> 1) & 3);
      af[m] = *(const bf16x8*)(&As[cur][r * 32 + slot * 8]);
    }
#pragma unroll
    for (int n = 0; n < 4; ++n) {
      const int r = wc * 64 + n * 16 + lr;
      const int slot = lks ^ ((r >> 1) & 3);
      bfr[n] = *(const bf16x8*)(&Bs[cur][r * 32 + slot * 8]);
    }
#pragma unroll
    for (int m = 0; m < 4; ++m)
#pragma unroll
      for (int n = 0; n < 4; ++n)
        acc[m][n] = __builtin_amdgcn_mfma_f32_16x16x32_bf16(af[m], bfr[n], acc[m][n], 0, 0, 0);
    __syncthreads();
    cur ^= 1;
  }

#pragma unroll
  for (int m = 0; m < 4; ++m)
#pragma unroll
    for (int n = 0; n < 4; ++n)
#pragma unroll
      for (int r = 0; r < 4; ++r) {
        const int row = tm * 128 + wr * 64 + m * 16 + (l >> 4) * 4 + r;
        const int col = tn * 128 + wc * 64 + n * 16 + lr;
        if (OBF) {
          ((unsigned short*)Cv)[bz * strideC + (size_t)row * LDCv + col] =
              f2bf(acc[m][n][r] * scale);
        } else {
          ((float*)Cv)[bz * strideC + (size_t)row * LDCv + col] = acc[m][n][r] * scale;
        }
      }
}

// ---------------- K3: v f32 -> bf16 (no transpose)
__global__ __launch_bounds__(256) void convert_v(
    const float* __restrict__ v, unsigned short* __restrict__ vB) {
  const size_t i8 = (size_t)blockIdx.x * 256 + threadIdx.x;
  const float4 a = *(const float4*)(v + i8 * 8);
  const float4 b = *(const float4*)(v + i8 * 8 + 4);
  bf16x8 o;
  o[0] = (short)f2bf(a.x); o[1] = (short)f2bf(a.y);
  o[2] = (short)f2bf(a.z); o[3] = (short)f2bf(a.w);
  o[4] = (short)f2bf(b.x); o[5] = (short)f2bf(b.y);
  o[6] = (short)f2bf(b.z); o[7] = (short)f2bf(b.w);
  *(bf16x8*)(vB + i8 * 8) = o;
}

// ---------------- K2: in-place softmax over b (16 values) at each (j,i)
__global__ __launch_bounds__(256) void softmax_b(unsigned short* __restrict__ SP) {
  const size_t off = ((size_t)blockIdx.x * 256 + threadIdx.x) * 8;
  bf16x8 s[BN];
#pragma unroll
  for (int b = 0; b < BN; ++b)
    s[b] = *(const bf16x8*)(SP + (size_t)b * (LN * LN) + off);
#pragma unroll
  for (int e = 0; e < 8; ++e) {
    float vv[BN];
#pragma unroll
    for (int b = 0; b < BN; ++b) vv[b] = bf2f((unsigned short)s[b][e]);
    float m = vv[0];
#pragma unroll
    for (int b = 1; b < BN; ++b) m = fmaxf(m, vv[b]);
    float tt[BN], sum = 0.f;
#pragma unroll
    for (int b = 0; b < BN; ++b) { tt[b] = __expf(vv[b] - m); sum += tt[b]; }
    const float inv = 1.f / sum;
#pragma unroll
    for (int b = 0; b < BN; ++b) s[b][e] = (short)f2bf(tt[b] * inv);
  }
#pragma unroll
  for (int b = 0; b < BN; ++b)
    *(bf16x8*)(SP + (size_t)b * (LN * LN) + off) = s[b];
}

extern "C" void kernel_launch(void* const* d_in, const int* in_sizes, int n_in,
                              void* d_out, int out_size, void* d_ws, size_t ws_size,
                              hipStream_t stream) {
  const float* q = (const float*)d_in[0];
  const float* k = (const float*)d_in[1];
  const float* v = (const float*)d_in[2];
  float* out = (float*)d_out;

  unsigned short* qT = (unsigned short*)d_ws;            // 16 MiB
  unsigned short* kT = qT + (size_t)BN * LN * CC;        // 16 MiB
  unsigned short* SP = kT + (size_t)BN * LN * CC;        // 32 MiB (S' then P)
  unsigned short* vB = qT;                               // overlay (qT dead after K1)

  transpose_convert64<<<dim3(LN / 64, CC / 64, BN * 2), 256, 0, stream>>>(q, k, qT, kT);
  // K1: S' = (qT . kT^T)/32, bf16. 1024 blocks, batch-pair per block, 32 steps.
  gemm_2bacc<<<dim3(16, 8, 8), 256, 0, stream>>>(
      qT, kT, SP, 0.03125f,
      (size_t)LN * CC, (size_t)LN * CC, (size_t)LN * LN);
  convert_v<<<dim3((BN * CC * LN) / 8 / 256), 256, 0, stream>>>(v, vB);
  softmax_b<<<dim3((LN * LN) / 8 / 256), 256, 0, stream>>>(SP);
  // K4: out = vB . P^T, f32. M=512, N=1024, K=1024.
  gemm_glds<1024, 1024, 1024, 1024, false, 8, 4, BN><<<dim3(8, 4, BN), 256, 0, stream>>>(
      vB, SP, (void*)out, 1.0f,
      (size_t)CC * LN, (size_t)LN * LN, (size_t)CC * LN);
}

// Round 16
// 93.494 us; speedup vs baseline: 1.4410x; 1.0649x over previous
//
#include <hip/hip_runtime.h>
#include <hip/hip_bf16.h>

// B=16, C=512, L=1024.
// score[b,i,j] = sum_c k[b,c,i]*q[b,c,j] / 32 ; P = softmax over b (axis=0!)
// out[b,c,j] = sum_i v[b,c,i]*P[b,i,j]
// Pipeline:
//   K0 transpose_convert: q,k f32 [b][c][l] -> qT,kT bf16 [b][l][c] (32-tile, R11)
//   K1 gemm_k1: S' = (qT.kT^T)/32, bf16; R10 core + LDS-REPACK COALESCED EPILOGUE
//        (single change under test: 16B bf16x8 stores instead of 16 scattered
//         2B stores -- isolating the bf16-store-path hypothesis for K1==40us)
//   K3 convert_v: v f32 -> vB bf16
//   K2 softmax_b: in-place softmax over b on S'
//   K4 gemm_glds: out = vB . P^T, f32 (unchanged, ~24us/716TF)
// GEMM core: 128x128, BK=32 dbuf (32KiB, 5/CU), global_load_lds w=16, XOR
// swizzle slot^=((row>>1)&3) on source AND ds_read (rule 21), XCD chunk remap.

#define LN 1024
#define CC 512
#define BN 16

typedef __attribute__((ext_vector_type(8))) short bf16x8;
typedef __attribute__((ext_vector_type(4))) float f32x4;

static __device__ __forceinline__ unsigned short f2bf(float x) {
  union { float f; unsigned u; } un; un.f = x;
  unsigned r = un.u + 0x7fffu + ((un.u >> 16) & 1u);   // RNE
  return (unsigned short)(r >> 16);
}
static __device__ __forceinline__ float bf2f(unsigned short h) {
  union { unsigned u; float f; } un; un.u = ((unsigned)h) << 16; return un.f;
}

// ---------------- K0: transpose-convert q,k (f32 [b][c][l]) -> bf16 [b][l][c]
__global__ __launch_bounds__(256) void transpose_convert(
    const float* __restrict__ q, const float* __restrict__ k,
    unsigned short* __restrict__ qT, unsigned short* __restrict__ kT) {
  __shared__ float tile[32][33];
  const int b   = blockIdx.z >> 1;
  const int mat = blockIdx.z & 1;
  const float* src = mat ? k : q;
  unsigned short* dst = mat ? kT : qT;
  const int l0 = blockIdx.x * 32, c0 = blockIdx.y * 32;
  const int t = threadIdx.x;
  const int ll = t & 31, cbase = t >> 5;
  const float* sp = src + ((size_t)b * CC + c0) * LN + l0;
#pragma unroll
  for (int r = 0; r < 4; ++r) {
    int cc = cbase + r * 8;
    tile[cc][ll] = sp[(size_t)cc * LN + ll];
  }
  __syncthreads();
  const int co = t & 31, lbase = t >> 5;
  unsigned short* dp = dst + ((size_t)b * LN + l0) * CC + c0;
#pragma unroll
  for (int r = 0; r < 4; ++r) {
    int lo = lbase + r * 8;
    dp[(size_t)lo * CC + co] = f2bf(tile[co][lo]);
  }
}

// ---------------- K1: 128^2 2-phase GEMM, bf16 out via LDS-repack epilogue.
// C[bz][row][col] = scale * sum_k A[bz][row][k]*B[bz][col][k]
__global__ __launch_bounds__(256, 5) void gemm_k1(
    const unsigned short* __restrict__ A, const unsigned short* __restrict__ B,
    unsigned short* __restrict__ C, float scale,
    size_t strideA, size_t strideB, size_t strideC) {
  __shared__ unsigned short LDSBUF[4][128 * 32];   // As=0,1  Bs=2,3 ; 32 KiB total
#define AsL(buf) (&LDSBUF[(buf)][0])
#define BsL(buf) (&LDSBUF[2 + (buf)][0])

  constexpr int NTN = 8, NTM = 8, NB = BN;
  constexpr int nwg = NTN * NTM * NB;          // 1024
  const int f = blockIdx.x + NTN * (blockIdx.y + NTM * blockIdx.z);
  const int wid = (f & 7) * (nwg >> 3) + (f >> 3);
  const int tn = wid % NTN;
  const int tm = (wid / NTN) % NTM;
  const int bz = wid / (NTN * NTM);

  const unsigned short* Ab = A + (size_t)bz * strideA;
  const unsigned short* Bb = B + (size_t)bz * strideB;
  const int t = threadIdx.x, w = t >> 6, l = t & 63;
  const int wr = w >> 1, wc = w & 1;
  const int lr = l & 15, lks = l >> 4;

  f32x4 acc[4][4];
#pragma unroll
  for (int m = 0; m < 4; ++m)
#pragma unroll
    for (int n = 0; n < 4; ++n) acc[m][n] = (f32x4){0.f, 0.f, 0.f, 0.f};

  const int srow = t >> 2, sslot = t & 3;

  auto STAGE = [&](int buf, int step) {
    const int c0 = step * 32;
#pragma unroll
    for (int qq = 0; qq < 2; ++qq) {
      const int row = qq * 64 + srow;
      const unsigned short* ga =
          Ab + (size_t)(tm * 128 + row) * CC + c0 + ((sslot ^ ((row >> 1) & 3)) * 8);
      __builtin_amdgcn_global_load_lds(
          (const __attribute__((address_space(1))) void*)ga,
          (__attribute__((address_space(3))) void*)&AsL(buf)[qq * 2048 + t * 8],
          16, 0, 0);
    }
#pragma unroll
    for (int qq = 0; qq < 2; ++qq) {
      const int row = qq * 64 + srow;
      const unsigned short* gb =
          Bb + (size_t)(tn * 128 + row) * CC + c0 + ((sslot ^ ((row >> 1) & 3)) * 8);
      __builtin_amdgcn_global_load_lds(
          (const __attribute__((address_space(1))) void*)gb,
          (__attribute__((address_space(3))) void*)&BsL(buf)[qq * 2048 + t * 8],
          16, 0, 0);
    }
  };

  STAGE(0, 0);
  __syncthreads();

  const int NSTEP = CC / 32;   // 16
  int cur = 0;
#pragma unroll 1
  for (int step = 0; step < NSTEP; ++step) {
    if (step + 1 < NSTEP) STAGE(cur ^ 1, step + 1);
    bf16x8 af[4], bfr[4];
#pragma unroll
    for (int m = 0; m < 4; ++m) {
      const int r = wr * 64 + m * 16 + lr;
      af[m] = *(const bf16x8*)(&AsL(cur)[r * 32 + ((lks ^ ((r >> 1) & 3)) * 8)]);
    }
#pragma unroll
    for (int n = 0; n < 4; ++n) {
      const int r = wc * 64 + n * 16 + lr;
      bfr[n] = *(const bf16x8*)(&BsL(cur)[r * 32 + ((lks ^ ((r >> 1) & 3)) * 8)]);
    }
#pragma unroll
    for (int m = 0; m < 4; ++m)
#pragma unroll
      for (int n = 0; n < 4; ++n)
        acc[m][n] = __builtin_amdgcn_mfma_f32_16x16x32_bf16(af[m], bfr[n], acc[m][n], 0, 0, 0);
    __syncthreads();
    cur ^= 1;
  }

  // ---- repack epilogue: fragments -> LDS (32KB = whole 128x128 bf16 tile),
  //      then fully-coalesced 16B stores.
  unsigned short* Cs = &LDSBUF[0][0];          // 16384 shorts
  // (last __syncthreads of the loop guarantees LDS is free)
#pragma unroll
  for (int m = 0; m < 4; ++m)
#pragma unroll
    for (int n = 0; n < 4; ++n)
#pragma unroll
      for (int r = 0; r < 4; ++r) {
        const int row = wr * 64 + m * 16 + (l >> 4) * 4 + r;
        const int col = wc * 64 + n * 16 + lr;
        Cs[row * 128 + col] = f2bf(acc[m][n][r] * scale);
      }
  __syncthreads();
  unsigned short* Cb = C + (size_t)bz * strideC + (size_t)(tm * 128) * LN + tn * 128;
#pragma unroll
  for (int it = 0; it < 8; ++it) {
    const int row = it * 16 + (t >> 4);
    const int c8 = (t & 15) * 8;
    *(bf16x8*)(Cb + (size_t)row * LN + c8) = *(const bf16x8*)(&Cs[row * 128 + c8]);
  }
#undef AsL
#undef BsL
}

// ---------------- K4: 128^2 2-phase batched GEMM (measured-good, unchanged)
template<int KD, int LDAv, int LDBv, int LDCv, bool OBF, int NTN, int NTM, int NB>
__global__ __launch_bounds__(256, 5) void gemm_glds(
    const unsigned short* __restrict__ A, const unsigned short* __restrict__ B,
    void* __restrict__ Cv, float scale,
    size_t strideA, size_t strideB, size_t strideC) {
  __shared__ unsigned short As[2][128 * 32];
  __shared__ unsigned short Bs[2][128 * 32];

  constexpr int nwg = NTN * NTM * NB;
  const int f = blockIdx.x + NTN * (blockIdx.y + NTM * blockIdx.z);
  const int wid = (f & 7) * (nwg >> 3) + (f >> 3);
  const int tn = wid % NTN;
  const int tm = (wid / NTN) % NTM;
  const int bz = wid / (NTN * NTM);

  const unsigned short* Ab = A + (size_t)bz * strideA;
  const unsigned short* Bb = B + (size_t)bz * strideB;
  const int t = threadIdx.x, w = t >> 6, l = t & 63;
  const int wr = w >> 1, wc = w & 1;
  const int lr = l & 15, lks = l >> 4;

  f32x4 acc[4][4];
#pragma unroll
  for (int m = 0; m < 4; ++m)
#pragma unroll
    for (int n = 0; n < 4; ++n) acc[m][n] = (f32x4){0.f, 0.f, 0.f, 0.f};

  const int srow = t >> 2, sslot = t & 3;

  auto STAGE = [&](int buf, int step) {
    const int c0 = step * 32;
#pragma unroll
    for (int qq = 0; qq < 2; ++qq) {
      const int row = qq * 64 + srow;
      const unsigned short* ga =
          Ab + (size_t)(tm * 128 + row) * LDAv + c0 + ((sslot ^ ((row >> 1) & 3)) * 8);
      __builtin_amdgcn_global_load_lds(
          (const __attribute__((address_space(1))) void*)ga,
          (__attribute__((address_space(3))) void*)&As[buf][qq * 2048 + t * 8],
          16, 0, 0);
    }
#pragma unroll
    for (int qq = 0; qq < 2; ++qq) {
      const int row = qq * 64 + srow;
      const unsigned short* gb =
          Bb + (size_t)(tn * 128 + row) * LDBv + c0 + ((sslot ^ ((row >> 1) & 3)) * 8);
      __builtin_amdgcn_global_load_lds(
          (const __attribute__((address_space(1))) void*)gb,
          (__attribute__((address_space(3))) void*)&Bs[buf][qq * 2048 + t * 8],
          16, 0, 0);
    }
  };

  STAGE(0, 0);
  __syncthreads();

  const int NSTEP = KD / 32;
  int cur = 0;
#pragma unroll 1
  for (int step = 0; step < NSTEP; ++step) {
    if (step + 1 < NSTEP) STAGE(cur ^ 1, step + 1);
    bf16x8 af[4], bfr[4];
#pragma unroll
    for (int m = 0; m < 4; ++m) {
      const int r = wr * 64 + m * 16 + lr;
      const int slot = lks ^ ((r >> 1) & 3);
      af[m] = *(const bf16x8*)(&As[cur][r * 32 + slot * 8]);
    }
#pragma unroll
    for (int n = 0; n < 4; ++n) {
      const int r = wc * 64 + n * 16 + lr;
      const int slot = lks ^ ((r >> 1) & 3);
      bfr[n] = *(const bf16x8*)(&Bs[cur][r * 32 + slot * 8]);
    }
#pragma unroll
    for (int m = 0; m < 4; ++m)
#pragma unroll
      for (int n = 0; n < 4; ++n)
        acc[m][n] = __builtin_amdgcn_mfma_f32_16x16x32_bf16(af[m], bfr[n], acc[m][n], 0, 0, 0);
    __syncthreads();
    cur ^= 1;
  }

#pragma unroll
  for (int m = 0; m < 4; ++m)
#pragma unroll
    for (int n = 0; n < 4; ++n)
#pragma unroll
      for (int r = 0; r < 4; ++r) {
        const int row = tm * 128 + wr * 64 + m * 16 + (l >> 4) * 4 + r;
        const int col = tn * 128 + wc * 64 + n * 16 + lr;
        if (OBF) {
          ((unsigned short*)Cv)[bz * strideC + (size_t)row * LDCv + col] =
              f2bf(acc[m][n][r] * scale);
        } else {
          ((float*)Cv)[bz * strideC + (size_t)row * LDCv + col] = acc[m][n][r] * scale;
        }
      }
}

// ---------------- K3: v f32 -> bf16 (no transpose)
__global__ __launch_bounds__(256) void convert_v(
    const float* __restrict__ v, unsigned short* __restrict__ vB) {
  const size_t i8 = (size_t)blockIdx.x * 256 + threadIdx.x;
  const float4 a = *(const float4*)(v + i8 * 8);
  const float4 b = *(const float4*)(v + i8 * 8 + 4);
  bf16x8 o;
  o[0] = (short)f2bf(a.x); o[1] = (short)f2bf(a.y);
  o[2] = (short)f2bf(a.z); o[3] = (short)f2bf(a.w);
  o[4] = (short)f2bf(b.x); o[5] = (short)f2bf(b.y);
  o[6] = (short)f2bf(b.z); o[7] = (short)f2bf(b.w);
  *(bf16x8*)(vB + i8 * 8) = o;
}

// ---------------- K2: in-place softmax over b (16 values) at each (j,i)
__global__ __launch_bounds__(256) void softmax_b(unsigned short* __restrict__ SP) {
  const size_t off = ((size_t)blockIdx.x * 256 + threadIdx.x) * 8;
  bf16x8 s[BN];
#pragma unroll
  for (int b = 0; b < BN; ++b)
    s[b] = *(const bf16x8*)(SP + (size_t)b * (LN * LN) + off);
#pragma unroll
  for (int e = 0; e < 8; ++e) {
    float vv[BN];
#pragma unroll
    for (int b = 0; b < BN; ++b) vv[b] = bf2f((unsigned short)s[b][e]);
    float m = vv[0];
#pragma unroll
    for (int b = 1; b < BN; ++b) m = fmaxf(m, vv[b]);
    float tt[BN], sum = 0.f;
#pragma unroll
    for (int b = 0; b < BN; ++b) { tt[b] = __expf(vv[b] - m); sum += tt[b]; }
    const float inv = 1.f / sum;
#pragma unroll
    for (int b = 0; b < BN; ++b) s[b][e] = (short)f2bf(tt[b] * inv);
  }
#pragma unroll
  for (int b = 0; b < BN; ++b)
    *(bf16x8*)(SP + (size_t)b * (LN * LN) + off) = s[b];
}

extern "C" void kernel_launch(void* const* d_in, const int* in_sizes, int n_in,
                              void* d_out, int out_size, void* d_ws, size_t ws_size,
                              hipStream_t stream) {
  const float* q = (const float*)d_in[0];
  const float* k = (const float*)d_in[1];
  const float* v = (const float*)d_in[2];
  float* out = (float*)d_out;

  unsigned short* qT = (unsigned short*)d_ws;            // 16 MiB
  unsigned short* kT = qT + (size_t)BN * LN * CC;        // 16 MiB
  unsigned short* SP = kT + (size_t)BN * LN * CC;        // 32 MiB (S' then P)
  unsigned short* vB = qT;                               // overlay (qT dead after K1)

  transpose_convert<<<dim3(LN / 32, CC / 32, BN * 2), 256, 0, stream>>>(q, k, qT, kT);
  // K1: S' = (qT . kT^T)/32, bf16, coalesced-epilogue.
  gemm_k1<<<dim3(8, 8, BN), 256, 0, stream>>>(
      qT, kT, SP, 0.03125f,
      (size_t)LN * CC, (size_t)LN * CC, (size_t)LN * LN);
  convert_v<<<dim3((BN * CC * LN) / 8 / 256), 256, 0, stream>>>(v, vB);
  softmax_b<<<dim3((LN * LN) / 8 / 256), 256, 0, stream>>>(SP);
  // K4: out = vB . P^T, f32. M=512, N=1024, K=1024.
  gemm_glds<1024, 1024, 1024, 1024, false, 8, 4, BN><<<dim3(8, 4, BN), 256, 0, stream>>>(
      vB, SP, (void*)out, 1.0f,
      (size_t)CC * LN, (size_t)LN * LN, (size_t)CC * LN);
}